// Round 1
// baseline (932.445 us; speedup 1.0000x reference)
//
#include <hip/hip_runtime.h>
#include <hip/hip_bf16.h>
#include <math.h>

#define B_  32
#define S_  2048
#define H_  1024
#define M_TOT (B_ * S_)   // 65536 rows

typedef __bf16 bf16x8 __attribute__((ext_vector_type(8)));
typedef float  f32x4  __attribute__((ext_vector_type(4)));

// f32 -> bf16 round-to-nearest-even (normals; inputs are finite)
__device__ __forceinline__ unsigned short f2bf(float f) {
    union { float f; unsigned int u; } v; v.f = f;
    unsigned int u = v.u;
    return (unsigned short)((u + 0x7fffu + ((u >> 16) & 1u)) >> 16);
}

__device__ __forceinline__ float bf2f(unsigned short s) {
    return __uint_as_float(((unsigned int)s) << 16);
}

// ---------------------------------------------------------------------------
// Kernel 1: mean over s  +  f32->bf16 convert of inputs into ws
// grid (32 b, 16 s-chunks), block 256. Each thread: one float4 column slot.
// ---------------------------------------------------------------------------
__global__ void k_meanconv(const float* __restrict__ x,
                           unsigned short* __restrict__ xbf,
                           float* __restrict__ meanOut /* d_out[0:32768], pre-zeroed */) {
    int b  = blockIdx.x;
    int sc = blockIdx.y;
    int t  = threadIdx.x;
    size_t base = ((size_t)b * S_ + (size_t)sc * 128) * H_;
    const float4* xr = (const float4*)(x + base);
    ushort4* xo = (ushort4*)(xbf + base);
    float a0 = 0.f, a1 = 0.f, a2 = 0.f, a3 = 0.f;
    for (int s = 0; s < 128; ++s) {
        float4 v = xr[(size_t)s * 256 + t];
        a0 += v.x; a1 += v.y; a2 += v.z; a3 += v.w;
        ushort4 o;
        o.x = f2bf(v.x); o.y = f2bf(v.y); o.z = f2bf(v.z); o.w = f2bf(v.w);
        xo[(size_t)s * 256 + t] = o;
    }
    const float scl = 1.0f / (float)S_;
    float* mp = meanOut + b * H_ + t * 4;
    atomicAdd(mp + 0, a0 * scl);
    atomicAdd(mp + 1, a1 * scl);
    atomicAdd(mp + 2, a2 * scl);
    atomicAdd(mp + 3, a3 * scl);
}

// ---------------------------------------------------------------------------
// Kernel 2: W1|W2 -> bf16 transposed  WT[n][k] = W(hop)[k][n],  n in [0,2048)
// grid 2048 (one n row per block), block 256.
// ---------------------------------------------------------------------------
__global__ void k_wconv(const float* __restrict__ W1,
                        const float* __restrict__ W2,
                        unsigned short* __restrict__ WT) {
    int n = blockIdx.x;
    int t = threadIdx.x;
    const float* src = (n < H_) ? (W1 + n) : (W2 + (n - H_));
    unsigned short* dst = WT + (size_t)n * H_;
    for (int kk = 0; kk < 4; ++kk) {
        int k = t + kk * 256;
        dst[k] = f2bf(src[(size_t)k * H_]);
    }
}

// ---------------------------------------------------------------------------
// Kernel 3: v_cat[b, hop*1024 + d] = tanh( (m_hop[b] @ Wm)[d] ) * Wh[d]
//   m_0 = mean*q ;  m_1 = 2*mean*q   (since u_att0 == mean_in)
// grid (32 b, 2 hop), block 256, f32 precision.
// ---------------------------------------------------------------------------
__global__ void k_vcat(const float* __restrict__ meanIn,
                       const float* __restrict__ q,
                       const float* __restrict__ Wm1, const float* __restrict__ Wh1,
                       const float* __restrict__ Wm2, const float* __restrict__ Wh2,
                       float* __restrict__ vcat) {
    int b   = blockIdx.x;
    int hop = blockIdx.y;
    int t   = threadIdx.x;
    __shared__ float mL[H_];
    float scale = (hop == 0) ? 1.0f : 2.0f;
    for (int i = t; i < H_; i += 256)
        mL[i] = meanIn[b * H_ + i] * q[b * H_ + i] * scale;
    __syncthreads();
    const float* Wm = hop ? Wm2 : Wm1;
    const float* Wh = hop ? Wh2 : Wh1;
    int d0 = t * 4;
    float a0 = 0.f, a1 = 0.f, a2 = 0.f, a3 = 0.f;
    for (int h = 0; h < H_; ++h) {
        float m = mL[h];
        float4 w = *(const float4*)(Wm + (size_t)h * H_ + d0);
        a0 += m * w.x; a1 += m * w.y; a2 += m * w.z; a3 += m * w.w;
    }
    float* vo = vcat + b * 2048 + hop * H_ + d0;
    vo[0] = tanhf(a0) * Wh[d0 + 0];
    vo[1] = tanhf(a1) * Wh[d0 + 1];
    vo[2] = tanhf(a2) * Wh[d0 + 2];
    vo[3] = tanhf(a3) * Wh[d0 + 3];
}

// ---------------------------------------------------------------------------
// Kernel 4: the big fused GEMM.
//   P = Xbf @ Wcat  (M=65536, N=2048 [hop1|hop2], K=1024), bf16 MFMA
//   epilogue: U[hop][row] += sum_n tanh(P[row,n]) * vcat[b,n]
// m97 structure: 128x128 tile, BK=32, global_load_lds width-16, 2-barrier loop.
// grid (16 n-tiles fastest, 512 m-tiles), block 256 (4 waves, 2x2, 64x64 each).
// ---------------------------------------------------------------------------
__global__ __launch_bounds__(256) void k_gemm(const unsigned short* __restrict__ Xbf,
                                              const unsigned short* __restrict__ WT,
                                              const float* __restrict__ vcat,
                                              float* __restrict__ U /* pre-zeroed */) {
    int nt = blockIdx.x;           // 0..15
    int mt = blockIdx.y;           // 0..511
    int m0 = mt * 128;
    int n0 = nt * 128;
    int t    = threadIdx.x;
    int lane = t & 63;
    int wave = t >> 6;
    int wm = wave >> 1, wn = wave & 1;
    int fr = lane & 15;            // fragment row/col within 16
    int fq = lane >> 4;            // quad 0..3

    __shared__ unsigned short As[128 * 32];
    __shared__ unsigned short Bs[128 * 32];

    f32x4 acc[4][4];
#pragma unroll
    for (int i = 0; i < 4; ++i)
#pragma unroll
        for (int j = 0; j < 4; ++j)
#pragma unroll
            for (int r = 0; r < 4; ++r) acc[i][j][r] = 0.0f;

    // staging: 512 16B-lane-loads per tile; 256 threads -> 2 insts each, per matrix
    int idx0 = t, idx1 = t + 256;
    int row0 = idx0 >> 2, kp0 = (idx0 & 3) * 8;
    int row1 = idx1 >> 2, kp1 = (idx1 & 3) * 8;
    const unsigned short* gA0 = Xbf + (size_t)(m0 + row0) * H_ + kp0;
    const unsigned short* gA1 = Xbf + (size_t)(m0 + row1) * H_ + kp1;
    const unsigned short* gB0 = WT  + (size_t)(n0 + row0) * H_ + kp0;
    const unsigned short* gB1 = WT  + (size_t)(n0 + row1) * H_ + kp1;
    unsigned short* lA0 = As + idx0 * 8;
    unsigned short* lA1 = As + idx1 * 8;
    unsigned short* lB0 = Bs + idx0 * 8;
    unsigned short* lB1 = Bs + idx1 * 8;

    // fragment LDS pointers: A[m=fr][k=fq*8+j], B(n-major)[n=fr][k=fq*8+j]
    const bf16x8* pa[4];
    const bf16x8* pb[4];
#pragma unroll
    for (int i = 0; i < 4; ++i)
        pa[i] = (const bf16x8*)(As + (wm * 64 + i * 16 + fr) * 32 + fq * 8);
#pragma unroll
    for (int j = 0; j < 4; ++j)
        pb[j] = (const bf16x8*)(Bs + (wn * 64 + j * 16 + fr) * 32 + fq * 8);

    for (int k0 = 0; k0 < H_; k0 += 32) {
        __builtin_amdgcn_global_load_lds((const __attribute__((address_space(1))) void*)(gA0 + k0),
                                         (__attribute__((address_space(3))) void*)lA0, 16, 0, 0);
        __builtin_amdgcn_global_load_lds((const __attribute__((address_space(1))) void*)(gA1 + k0),
                                         (__attribute__((address_space(3))) void*)lA1, 16, 0, 0);
        __builtin_amdgcn_global_load_lds((const __attribute__((address_space(1))) void*)(gB0 + k0),
                                         (__attribute__((address_space(3))) void*)lB0, 16, 0, 0);
        __builtin_amdgcn_global_load_lds((const __attribute__((address_space(1))) void*)(gB1 + k0),
                                         (__attribute__((address_space(3))) void*)lB1, 16, 0, 0);
        __syncthreads();   // drains vmcnt (staging complete)
        bf16x8 af[4], bg[4];
#pragma unroll
        for (int i = 0; i < 4; ++i) af[i] = *pa[i];
#pragma unroll
        for (int j = 0; j < 4; ++j) bg[j] = *pb[j];
#pragma unroll
        for (int i = 0; i < 4; ++i)
#pragma unroll
            for (int j = 0; j < 4; ++j)
                acc[i][j] = __builtin_amdgcn_mfma_f32_16x16x32_bf16(af[i], bg[j], acc[i][j], 0, 0, 0);
        __syncthreads();   // protect LDS before next stage overwrites
    }

    // epilogue: tanh, weight by v, reduce the 128 columns of this block
    int b   = m0 >> 11;            // 2048 rows per batch; tiles never straddle b
    int hop = n0 >> 10;
    float vv[4];
#pragma unroll
    for (int j = 0; j < 4; ++j)
        vv[j] = vcat[b * 2048 + n0 + wn * 64 + j * 16 + fr];

#pragma unroll
    for (int i = 0; i < 4; ++i) {
#pragma unroll
        for (int r = 0; r < 4; ++r) {
            float sum = tanhf(acc[i][0][r]) * vv[0]
                      + tanhf(acc[i][1][r]) * vv[1]
                      + tanhf(acc[i][2][r]) * vv[2]
                      + tanhf(acc[i][3][r]) * vv[3];
            // reduce across the 16 lanes (fr) that share this row
            sum += __shfl_xor(sum, 1);
            sum += __shfl_xor(sum, 2);
            sum += __shfl_xor(sum, 4);
            sum += __shfl_xor(sum, 8);
            if (fr == 0) {
                int row = m0 + wm * 64 + i * 16 + fq * 4 + r;
                atomicAdd(&U[(size_t)hop * M_TOT + row], sum);
            }
        }
    }
}

// ---------------------------------------------------------------------------
// Kernel 5: softmax over s per (b,hop).  grid 64, block 256.
// ---------------------------------------------------------------------------
__global__ void k_softmax(const float* __restrict__ U, float* __restrict__ alpha) {
    int id  = blockIdx.x;
    int hop = id >> 5, b = id & 31;
    int t = threadIdx.x;
    const float* u = U + (size_t)hop * M_TOT + (size_t)b * S_;
    float* al = alpha + (size_t)hop * M_TOT + (size_t)b * S_;
    float v[8];
    float mx = -1e30f;
#pragma unroll
    for (int i = 0; i < 8; ++i) { v[i] = u[t + i * 256]; mx = fmaxf(mx, v[i]); }
    __shared__ float red[256];
    red[t] = mx; __syncthreads();
    for (int s = 128; s > 0; s >>= 1) {
        if (t < s) red[t] = fmaxf(red[t], red[t + s]);
        __syncthreads();
    }
    mx = red[0]; __syncthreads();
    float sum = 0.f;
#pragma unroll
    for (int i = 0; i < 8; ++i) { v[i] = expf(v[i] - mx); sum += v[i]; }
    red[t] = sum; __syncthreads();
    for (int s = 128; s > 0; s >>= 1) {
        if (t < s) red[t] += red[t + s];
        __syncthreads();
    }
    float inv = 1.0f / red[0];
#pragma unroll
    for (int i = 0; i < 8; ++i) al[t + i * 256] = v[i] * inv;
}

// ---------------------------------------------------------------------------
// Kernel 6: u_att = sum_s inputs[b,s,:] * alpha[b,s]  (both hops, bf16 inputs)
// grid (32 b, 16 s-chunks), block 256.
// ---------------------------------------------------------------------------
__global__ void k_wsum(const unsigned short* __restrict__ Xbf,
                       const float* __restrict__ alpha,
                       float* __restrict__ out1 /* pre-zeroed */,
                       float* __restrict__ out2 /* pre-zeroed */) {
    int b  = blockIdx.x;
    int sc = blockIdx.y;
    int t  = threadIdx.x;
    __shared__ float a1[128], a2[128];
    int s0 = sc * 128;
    if (t < 128)      a1[t]       = alpha[(size_t)b * S_ + s0 + t];
    else              a2[t - 128] = alpha[(size_t)M_TOT + (size_t)b * S_ + s0 + (t - 128)];
    __syncthreads();
    const ushort4* xr = (const ushort4*)(Xbf + ((size_t)b * S_ + s0) * H_);
    float x0a = 0.f, x1a = 0.f, x2a = 0.f, x3a = 0.f;
    float x0b = 0.f, x1b = 0.f, x2b = 0.f, x3b = 0.f;
    for (int s = 0; s < 128; ++s) {
        ushort4 u = xr[(size_t)s * 256 + t];
        float f0 = bf2f(u.x), f1 = bf2f(u.y), f2 = bf2f(u.z), f3 = bf2f(u.w);
        float w1 = a1[s], w2 = a2[s];
        x0a += f0 * w1; x1a += f1 * w1; x2a += f2 * w1; x3a += f3 * w1;
        x0b += f0 * w2; x1b += f1 * w2; x2b += f2 * w2; x3b += f3 * w2;
    }
    float* o1 = out1 + b * H_ + t * 4;
    float* o2 = out2 + b * H_ + t * 4;
    atomicAdd(o1 + 0, x0a); atomicAdd(o1 + 1, x1a);
    atomicAdd(o1 + 2, x2a); atomicAdd(o1 + 3, x3a);
    atomicAdd(o2 + 0, x0b); atomicAdd(o2 + 1, x1b);
    atomicAdd(o2 + 2, x2b); atomicAdd(o2 + 3, x3b);
}

// ---------------------------------------------------------------------------
extern "C" void kernel_launch(void* const* d_in, const int* in_sizes, int n_in,
                              void* d_out, int out_size, void* d_ws, size_t ws_size,
                              hipStream_t stream) {
    const float* inputs = (const float*)d_in[0];
    const float* q      = (const float*)d_in[1];
    const float* W1     = (const float*)d_in[2];
    const float* Wm1    = (const float*)d_in[3];
    const float* Wh1    = (const float*)d_in[4];
    const float* W2     = (const float*)d_in[5];
    const float* Wm2    = (const float*)d_in[6];
    const float* Wh2    = (const float*)d_in[7];
    float* out = (float*)d_out;     // [3,B,H]: mean | u_att1 | u_att2

    // workspace layout (bytes); total ~133.3 MiB
    char* ws = (char*)d_ws;
    unsigned short* Xbf  = (unsigned short*)(ws);                 // 134217728 B
    unsigned short* WT   = (unsigned short*)(ws + 134217728);     //   4194304 B
    float*          vcat = (float*)(ws + 138412032);              //    262144 B
    float*          U    = (float*)(ws + 138674176);              //    524288 B
    float*          alph = (float*)(ws + 139198464);              //    524288 B

    hipMemsetAsync(d_out, 0, (size_t)out_size * sizeof(float), stream);
    hipMemsetAsync(U, 0, (size_t)2 * M_TOT * sizeof(float), stream);

    k_meanconv<<<dim3(32, 16), 256, 0, stream>>>(inputs, Xbf, out);
    k_wconv  <<<dim3(2048),    256, 0, stream>>>(W1, W2, WT);
    k_vcat   <<<dim3(32, 2),   256, 0, stream>>>(out, q, Wm1, Wh1, Wm2, Wh2, vcat);
    k_gemm   <<<dim3(16, 512), 256, 0, stream>>>(Xbf, WT, vcat, U);
    k_softmax<<<dim3(64),      256, 0, stream>>>(U, alph);
    k_wsum   <<<dim3(32, 16),  256, 0, stream>>>(Xbf, alph, out + 32768, out + 65536);
}

// Round 2
// 869.977 us; speedup vs baseline: 1.0718x; 1.0718x over previous
//
#include <hip/hip_runtime.h>
#include <hip/hip_bf16.h>
#include <math.h>

#define B_  32
#define S_  2048
#define H_  1024
#define M_TOT (B_ * S_)   // 65536 rows

typedef __bf16 bf16x8 __attribute__((ext_vector_type(8)));
typedef float  f32x4  __attribute__((ext_vector_type(4)));

// f32 -> bf16 round-to-nearest-even
__device__ __forceinline__ unsigned short f2bf(float f) {
    union { float f; unsigned int u; } v; v.f = f;
    unsigned int u = v.u;
    return (unsigned short)((u + 0x7fffu + ((u >> 16) & 1u)) >> 16);
}

__device__ __forceinline__ float bf2f(unsigned short s) {
    return __uint_as_float(((unsigned int)s) << 16);
}

// tanh via exp2-based expf: ~6 VALU insts, saturates correctly for |x| large
__device__ __forceinline__ float fast_tanh(float x) {
    float e = __expf(2.0f * x);
    return 1.0f - 2.0f / (e + 1.0f);
}

// ---------------------------------------------------------------------------
// Kernel 1: mean over s + f32->bf16 convert. grid (32 b, 64 sc of 32 rows).
// ---------------------------------------------------------------------------
__global__ void k_meanconv(const float* __restrict__ x,
                           unsigned short* __restrict__ xbf,
                           float* __restrict__ meanOut /* pre-zeroed */) {
    int b  = blockIdx.x;
    int sc = blockIdx.y;
    int t  = threadIdx.x;
    size_t base = ((size_t)b * S_ + (size_t)sc * 32) * H_;
    const float4* xr = (const float4*)(x + base);
    ushort4* xo = (ushort4*)(xbf + base);
    float a0 = 0.f, a1 = 0.f, a2 = 0.f, a3 = 0.f;
    for (int s = 0; s < 32; ++s) {
        float4 v = xr[(size_t)s * 256 + t];
        a0 += v.x; a1 += v.y; a2 += v.z; a3 += v.w;
        ushort4 o;
        o.x = f2bf(v.x); o.y = f2bf(v.y); o.z = f2bf(v.z); o.w = f2bf(v.w);
        xo[(size_t)s * 256 + t] = o;
    }
    const float scl = 1.0f / (float)S_;
    float* mp = meanOut + b * H_ + t * 4;
    atomicAdd(mp + 0, a0 * scl);
    atomicAdd(mp + 1, a1 * scl);
    atomicAdd(mp + 2, a2 * scl);
    atomicAdd(mp + 3, a3 * scl);
}

// ---------------------------------------------------------------------------
// Kernel 2: W1|W2 -> bf16 transposed  WT[n][k] = W(hop)[k][n]
// ---------------------------------------------------------------------------
__global__ void k_wconv(const float* __restrict__ W1,
                        const float* __restrict__ W2,
                        unsigned short* __restrict__ WT) {
    int n = blockIdx.x;
    int t = threadIdx.x;
    const float* src = (n < H_) ? (W1 + n) : (W2 + (n - H_));
    unsigned short* dst = WT + (size_t)n * H_;
    for (int kk = 0; kk < 4; ++kk) {
        int k = t + kk * 256;
        dst[k] = f2bf(src[(size_t)k * H_]);
    }
}

// ---------------------------------------------------------------------------
// Kernel 3a: partial (m_hop[b] @ Wm) over an H-chunk -> atomicAdd into vtmp
//   m_0 = mean*q ;  m_1 = 2*mean*q.   grid (32 b, 2 hop, 8 hc), block 256.
// ---------------------------------------------------------------------------
__global__ void k_vpart(const float* __restrict__ meanIn,
                        const float* __restrict__ q,
                        const float* __restrict__ Wm1,
                        const float* __restrict__ Wm2,
                        float* __restrict__ vtmp /* pre-zeroed */) {
    int b   = blockIdx.x;
    int hop = blockIdx.y;
    int hc  = blockIdx.z;
    int t   = threadIdx.x;
    __shared__ float mL[128];
    float scale = (hop == 0) ? 1.0f : 2.0f;
    int h0 = hc * 128;
    if (t < 128)
        mL[t] = meanIn[b * H_ + h0 + t] * q[b * H_ + h0 + t] * scale;
    __syncthreads();
    const float* Wm = hop ? Wm2 : Wm1;
    int d0 = t * 4;
    float a0 = 0.f, a1 = 0.f, a2 = 0.f, a3 = 0.f;
    for (int h = 0; h < 128; ++h) {
        float m = mL[h];
        float4 w = *(const float4*)(Wm + (size_t)(h0 + h) * H_ + d0);
        a0 += m * w.x; a1 += m * w.y; a2 += m * w.z; a3 += m * w.w;
    }
    float* vo = vtmp + b * 2048 + hop * H_ + d0;
    atomicAdd(vo + 0, a0);
    atomicAdd(vo + 1, a1);
    atomicAdd(vo + 2, a2);
    atomicAdd(vo + 3, a3);
}

// Kernel 3b: vcat = tanh(vtmp) * Wh.  grid 256, block 256.
__global__ void k_vfin(const float* __restrict__ vtmp,
                       const float* __restrict__ Wh1,
                       const float* __restrict__ Wh2,
                       float* __restrict__ vcat) {
    int i = blockIdx.x * 256 + threadIdx.x;   // [0, 65536)
    int hop = (i >> 10) & 1;
    int d = i & 1023;
    const float* Wh = hop ? Wh2 : Wh1;
    vcat[i] = tanhf(vtmp[i]) * Wh[d];
}

// ---------------------------------------------------------------------------
// Kernel 4: fused GEMM  P = Xbf @ WT^T (M=65536, N=2048, K=1024), bf16 MFMA
//   epilogue: U[hop][row] += sum_n fast_tanh(P[row,n]) * vcat[b,n]
// Swizzled LDS: chunk (row, kc) stored at slot (kc + (row>>1)) & 3 within the
// row's 64B — kills the 8-way quarter-wave bank conflict (reads become 2-way).
// ---------------------------------------------------------------------------
__global__ __launch_bounds__(256) void k_gemm(const unsigned short* __restrict__ Xbf,
                                              const unsigned short* __restrict__ WT,
                                              const float* __restrict__ vcat,
                                              float* __restrict__ U /* pre-zeroed */) {
    int nt = blockIdx.x;           // 0..15
    int mt = blockIdx.y;           // 0..511
    int m0 = mt * 128;
    int n0 = nt * 128;
    int t    = threadIdx.x;
    int lane = t & 63;
    int wave = t >> 6;
    int wm = wave >> 1, wn = wave & 1;
    int fr = lane & 15;            // fragment row within 16
    int fq = lane >> 4;            // quad 0..3 (k-chunk)

    __shared__ unsigned short As[128 * 32];
    __shared__ unsigned short Bs[128 * 32];

    f32x4 acc[4][4];
#pragma unroll
    for (int i = 0; i < 4; ++i)
#pragma unroll
        for (int j = 0; j < 4; ++j)
#pragma unroll
            for (int r = 0; r < 4; ++r) acc[i][j][r] = 0.0f;

    // staging: lane idx covers (row = idx>>2, slot = idx&3); the slot holds
    // global k-chunk kc = (slot - (row>>1)) & 3  (swizzle inverse)
    int idx0 = t, idx1 = t + 256;
    int row0 = idx0 >> 2, kc0 = ((idx0 & 3) - ((row0 >> 1) & 3)) & 3;
    int row1 = idx1 >> 2, kc1 = ((idx1 & 3) - ((row1 >> 1) & 3)) & 3;
    const unsigned short* gA0 = Xbf + (size_t)(m0 + row0) * H_ + kc0 * 8;
    const unsigned short* gA1 = Xbf + (size_t)(m0 + row1) * H_ + kc1 * 8;
    const unsigned short* gB0 = WT  + (size_t)(n0 + row0) * H_ + kc0 * 8;
    const unsigned short* gB1 = WT  + (size_t)(n0 + row1) * H_ + kc1 * 8;
    unsigned short* lA0 = As + idx0 * 8;
    unsigned short* lA1 = As + idx1 * 8;
    unsigned short* lB0 = Bs + idx0 * 8;
    unsigned short* lB1 = Bs + idx1 * 8;

    // fragment read: row = wtile + i*16 + fr, want kc = fq
    //   -> slot = (fq + (row>>1)) & 3 = (fq + (fr>>1)) & 3   (tile offs ≡ 0 mod 8)
    int slotR = (fq + ((fr >> 1) & 3)) & 3;
    const bf16x8* pa[4];
    const bf16x8* pb[4];
#pragma unroll
    for (int i = 0; i < 4; ++i)
        pa[i] = (const bf16x8*)(As + ((wm * 64 + i * 16 + fr) * 4 + slotR) * 8);
#pragma unroll
    for (int j = 0; j < 4; ++j)
        pb[j] = (const bf16x8*)(Bs + ((wn * 64 + j * 16 + fr) * 4 + slotR) * 8);

    for (int k0 = 0; k0 < H_; k0 += 32) {
        __builtin_amdgcn_global_load_lds((const __attribute__((address_space(1))) void*)(gA0 + k0),
                                         (__attribute__((address_space(3))) void*)lA0, 16, 0, 0);
        __builtin_amdgcn_global_load_lds((const __attribute__((address_space(1))) void*)(gA1 + k0),
                                         (__attribute__((address_space(3))) void*)lA1, 16, 0, 0);
        __builtin_amdgcn_global_load_lds((const __attribute__((address_space(1))) void*)(gB0 + k0),
                                         (__attribute__((address_space(3))) void*)lB0, 16, 0, 0);
        __builtin_amdgcn_global_load_lds((const __attribute__((address_space(1))) void*)(gB1 + k0),
                                         (__attribute__((address_space(3))) void*)lB1, 16, 0, 0);
        __syncthreads();   // drains vmcnt (staging complete)
        bf16x8 af[4], bg[4];
#pragma unroll
        for (int i = 0; i < 4; ++i) af[i] = *pa[i];
#pragma unroll
        for (int j = 0; j < 4; ++j) bg[j] = *pb[j];
#pragma unroll
        for (int i = 0; i < 4; ++i)
#pragma unroll
            for (int j = 0; j < 4; ++j)
                acc[i][j] = __builtin_amdgcn_mfma_f32_16x16x32_bf16(af[i], bg[j], acc[i][j], 0, 0, 0);
        __syncthreads();   // protect LDS before next stage overwrites
    }

    // epilogue: tanh, weight by v, reduce 128 columns of this block
    int b   = m0 >> 11;            // 2048 rows per batch; tiles never straddle b
    int hop = n0 >> 10;
    float vv[4];
#pragma unroll
    for (int j = 0; j < 4; ++j)
        vv[j] = vcat[b * 2048 + n0 + wn * 64 + j * 16 + fr];

#pragma unroll
    for (int i = 0; i < 4; ++i) {
#pragma unroll
        for (int r = 0; r < 4; ++r) {
            float sum = fast_tanh(acc[i][0][r]) * vv[0]
                      + fast_tanh(acc[i][1][r]) * vv[1]
                      + fast_tanh(acc[i][2][r]) * vv[2]
                      + fast_tanh(acc[i][3][r]) * vv[3];
            sum += __shfl_xor(sum, 1);
            sum += __shfl_xor(sum, 2);
            sum += __shfl_xor(sum, 4);
            sum += __shfl_xor(sum, 8);
            if (fr == 0) {
                int row = m0 + wm * 64 + i * 16 + fq * 4 + r;
                atomicAdd(&U[(size_t)hop * M_TOT + row], sum);
            }
        }
    }
}

// ---------------------------------------------------------------------------
// Kernel 5: softmax over s per (b,hop).  grid 64, block 256.
// ---------------------------------------------------------------------------
__global__ void k_softmax(const float* __restrict__ U, float* __restrict__ alpha) {
    int id  = blockIdx.x;
    int hop = id >> 5, b = id & 31;
    int t = threadIdx.x;
    const float* u = U + (size_t)hop * M_TOT + (size_t)b * S_;
    float* al = alpha + (size_t)hop * M_TOT + (size_t)b * S_;
    float v[8];
    float mx = -1e30f;
#pragma unroll
    for (int i = 0; i < 8; ++i) { v[i] = u[t + i * 256]; mx = fmaxf(mx, v[i]); }
    __shared__ float red[256];
    red[t] = mx; __syncthreads();
    for (int s = 128; s > 0; s >>= 1) {
        if (t < s) red[t] = fmaxf(red[t], red[t + s]);
        __syncthreads();
    }
    mx = red[0]; __syncthreads();
    float sum = 0.f;
#pragma unroll
    for (int i = 0; i < 8; ++i) { v[i] = expf(v[i] - mx); sum += v[i]; }
    red[t] = sum; __syncthreads();
    for (int s = 128; s > 0; s >>= 1) {
        if (t < s) red[t] += red[t + s];
        __syncthreads();
    }
    float inv = 1.0f / red[0];
#pragma unroll
    for (int i = 0; i < 8; ++i) al[t + i * 256] = v[i] * inv;
}

// ---------------------------------------------------------------------------
// Kernel 6: u_att = sum_s inputs[b,s,:] * alpha[b,s]. grid (32 b, 64 sc of 32).
// ---------------------------------------------------------------------------
__global__ void k_wsum(const unsigned short* __restrict__ Xbf,
                       const float* __restrict__ alpha,
                       float* __restrict__ out1 /* pre-zeroed */,
                       float* __restrict__ out2 /* pre-zeroed */) {
    int b  = blockIdx.x;
    int sc = blockIdx.y;
    int t  = threadIdx.x;
    __shared__ float a1[32], a2[32];
    int s0 = sc * 32;
    if (t < 32)       a1[t]      = alpha[(size_t)b * S_ + s0 + t];
    else if (t < 64)  a2[t - 32] = alpha[(size_t)M_TOT + (size_t)b * S_ + s0 + (t - 32)];
    __syncthreads();
    const ushort4* xr = (const ushort4*)(Xbf + ((size_t)b * S_ + s0) * H_);
    float x0a = 0.f, x1a = 0.f, x2a = 0.f, x3a = 0.f;
    float x0b = 0.f, x1b = 0.f, x2b = 0.f, x3b = 0.f;
    for (int s = 0; s < 32; ++s) {
        ushort4 u = xr[(size_t)s * 256 + t];
        float f0 = bf2f(u.x), f1 = bf2f(u.y), f2 = bf2f(u.z), f3 = bf2f(u.w);
        float w1 = a1[s], w2 = a2[s];
        x0a += f0 * w1; x1a += f1 * w1; x2a += f2 * w1; x3a += f3 * w1;
        x0b += f0 * w2; x1b += f1 * w2; x2b += f2 * w2; x3b += f3 * w2;
    }
    float* o1 = out1 + b * H_ + t * 4;
    float* o2 = out2 + b * H_ + t * 4;
    atomicAdd(o1 + 0, x0a); atomicAdd(o1 + 1, x1a);
    atomicAdd(o1 + 2, x2a); atomicAdd(o1 + 3, x3a);
    atomicAdd(o2 + 0, x0b); atomicAdd(o2 + 1, x1b);
    atomicAdd(o2 + 2, x2b); atomicAdd(o2 + 3, x3b);
}

// ---------------------------------------------------------------------------
extern "C" void kernel_launch(void* const* d_in, const int* in_sizes, int n_in,
                              void* d_out, int out_size, void* d_ws, size_t ws_size,
                              hipStream_t stream) {
    const float* inputs = (const float*)d_in[0];
    const float* q      = (const float*)d_in[1];
    const float* W1     = (const float*)d_in[2];
    const float* Wm1    = (const float*)d_in[3];
    const float* Wh1    = (const float*)d_in[4];
    const float* W2     = (const float*)d_in[5];
    const float* Wm2    = (const float*)d_in[6];
    const float* Wh2    = (const float*)d_in[7];
    float* out = (float*)d_out;     // [3,B,H]: mean | u_att1 | u_att2

    // workspace layout (bytes); total ~133.5 MiB + 0.25 MiB
    char* ws = (char*)d_ws;
    unsigned short* Xbf  = (unsigned short*)(ws);                 // 134217728 B
    unsigned short* WT   = (unsigned short*)(ws + 134217728);     //   4194304 B
    float*          vcat = (float*)(ws + 138412032);              //    262144 B
    float*          U    = (float*)(ws + 138674176);              //    524288 B
    float*          alph = (float*)(ws + 139198464);              //    524288 B
    float*          vtmp = (float*)(ws + 139722752);              //    262144 B

    hipMemsetAsync(d_out, 0, (size_t)out_size * sizeof(float), stream);
    // zero U + alph + vtmp in one shot (contiguous region)
    hipMemsetAsync(U, 0, 524288 + 524288 + 262144, stream);

    k_meanconv<<<dim3(32, 64), 256, 0, stream>>>(inputs, Xbf, out);
    k_wconv  <<<dim3(2048),    256, 0, stream>>>(W1, W2, WT);
    k_vpart  <<<dim3(32, 2, 8), 256, 0, stream>>>(out, q, Wm1, Wm2, vtmp);
    k_vfin   <<<dim3(256),     256, 0, stream>>>(vtmp, Wh1, Wh2, vcat);
    k_gemm   <<<dim3(16, 512), 256, 0, stream>>>(Xbf, WT, vcat, U);
    k_softmax<<<dim3(64),      256, 0, stream>>>(U, alph);
    k_wsum   <<<dim3(32, 64),  256, 0, stream>>>(Xbf, alph, out + 32768, out + 65536);
}